// Round 1
// baseline (299.480 us; speedup 1.0000x reference)
//
#include <hip/hip_runtime.h>

// PPNM layer: out = m + b_s[:,None] * m*m, m = x @ W
//   x: [B, 16] fp32, W: [16, 224] fp32, b_s: [B] fp32, out: [B, 224] fp32
//
// Memory-bound: 235 MB write + ~18 MB read => ~40 us floor at 6.3 TB/s.
// Each thread owns W[:, 4g:4g+4] in registers (64 VGPRs, loaded once,
// amortized over a grid-stride loop across pixels). Block = 224 threads
// = 4 pixel rows x 56 float4 band-groups -> block writes 3584 contiguous
// bytes per tile (perfectly coalesced).

#define LBANDS 224
#define EMEMB  16
#define GROUPS 56   // LBANDS / 4
#define PROWS  4    // pixel rows per block tile
#define NTHREADS (GROUPS * PROWS)  // 224

__global__ __launch_bounds__(NTHREADS) void ppnm_kernel(
    const float* __restrict__ x,    // [B, 16]
    const float* __restrict__ w,    // [16, 224]
    const float* __restrict__ bs,   // [B]
    float* __restrict__ out,        // [B, 224]
    int B)
{
    const int t  = threadIdx.x;
    const int g  = t % GROUPS;   // band group: bands [4g, 4g+4)
    const int pr = t / GROUPS;   // pixel row within tile: 0..3

    // W fragment for this thread's band group: Wf[k] = w[k][4g..4g+3].
    // 14 KB array, L2/L3 resident after first block touches it.
    float4 Wf[EMEMB];
    #pragma unroll
    for (int k = 0; k < EMEMB; ++k) {
        Wf[k] = *reinterpret_cast<const float4*>(w + k * LBANDS + 4 * g);
    }

    const int tiles = B / PROWS;  // 65536 for B=262144
    for (int tile = blockIdx.x; tile < tiles; tile += gridDim.x) {
        const int p = tile * PROWS + pr;

        const float b = bs[p];

        // x row: 4 float4 loads; broadcast across the 56 threads sharing p.
        const float4* xr = reinterpret_cast<const float4*>(x + p * EMEMB);
        const float4 xa = xr[0];
        const float4 xb = xr[1];
        const float4 xc = xr[2];
        const float4 xd = xr[3];
        float xv[EMEMB] = { xa.x, xa.y, xa.z, xa.w,
                            xb.x, xb.y, xb.z, xb.w,
                            xc.x, xc.y, xc.z, xc.w,
                            xd.x, xd.y, xd.z, xd.w };

        float4 acc = make_float4(0.f, 0.f, 0.f, 0.f);
        #pragma unroll
        for (int k = 0; k < EMEMB; ++k) {
            acc.x = fmaf(xv[k], Wf[k].x, acc.x);
            acc.y = fmaf(xv[k], Wf[k].y, acc.y);
            acc.z = fmaf(xv[k], Wf[k].z, acc.z);
            acc.w = fmaf(xv[k], Wf[k].w, acc.w);
        }

        // out = m + b * m*m  (exactly per reference: mat + b_s[:,None]*mat^2)
        float4 r;
        r.x = fmaf(b * acc.x, acc.x, acc.x);
        r.y = fmaf(b * acc.y, acc.y, acc.y);
        r.z = fmaf(b * acc.z, acc.z, acc.z);
        r.w = fmaf(b * acc.w, acc.w, acc.w);

        *reinterpret_cast<float4*>(out + p * LBANDS + 4 * g) = r;
    }
}

extern "C" void kernel_launch(void* const* d_in, const int* in_sizes, int n_in,
                              void* d_out, int out_size, void* d_ws, size_t ws_size,
                              hipStream_t stream) {
    const float* x  = (const float*)d_in[0];   // [B, 16]
    const float* w  = (const float*)d_in[1];   // [16, 224]
    const float* bs = (const float*)d_in[2];   // [B]
    float* out = (float*)d_out;

    const int B = in_sizes[2];                 // 262144

    // 2048 blocks: ~4-5 blocks/CU resident, 32 tiles each -> W-fragment
    // load amortized; per-block W L2 traffic negligible (29 MB total).
    const int grid = 2048;
    ppnm_kernel<<<grid, NTHREADS, 0, stream>>>(x, w, bs, out, B);
}

// Round 2
// 295.405 us; speedup vs baseline: 1.0138x; 1.0138x over previous
//
#include <hip/hip_runtime.h>

// PPNM layer: out = m + b_s[:,None] * m*m, m = x @ W
//   x: [B, 16] fp32, W: [16, 224] fp32, b_s: [B] fp32, out: [B, 224] fp32
//
// Memory-bound: 235 MB write + ~18 MB read => ~40 us floor at 6.3 TB/s.
//
// R1 changes vs R0 (which ran ~115 us kernel-proper):
//  - Block 224 -> 448 threads: 7 FULL waves (was 3.5 -> partial wave 3).
//    Mapping t = pr*56 + g keeps each wave's stores 1024 contiguous bytes.
//  - __launch_bounds__(448, 4): cap VGPRs at 128 -> 2 blocks/CU = 14 waves/CU.
//  - Explicit next-tile x/bs prefetch: global-load latency (L3 ~600 cy)
//    overlaps the 64-FMA chain + store instead of serializing per tile.

#define LBANDS 224
#define EMEMB  16
#define GROUPS 56                  // LBANDS / 4
#define PROWS  8                   // pixel rows per block tile
#define NTHREADS (GROUPS * PROWS)  // 448 = 7 full waves

__global__ __launch_bounds__(NTHREADS, 4) void ppnm_kernel(
    const float* __restrict__ x,    // [B, 16]
    const float* __restrict__ w,    // [16, 224]
    const float* __restrict__ bs,   // [B]
    float* __restrict__ out,        // [B, 224]
    int B)
{
    const int t  = threadIdx.x;
    const int g  = t % GROUPS;   // band group: bands [4g, 4g+4)
    const int pr = t / GROUPS;   // pixel row within tile: 0..7

    // W fragment for this thread's band group: Wf[k] = w[k][4g..4g+3].
    // 64 VGPRs; loaded once from L2, amortized over the grid-stride loop.
    float4 Wf[EMEMB];
    #pragma unroll
    for (int k = 0; k < EMEMB; ++k) {
        Wf[k] = *reinterpret_cast<const float4*>(w + k * LBANDS + 4 * g);
    }

    const int tiles = B / PROWS;   // 32768 for B=262144
    int tile = blockIdx.x;
    if (tile >= tiles) return;

    // --- prefetch first tile's x row + b ---
    int p = tile * PROWS + pr;
    const float4* xr = reinterpret_cast<const float4*>(x + p * EMEMB);
    float4 xa = xr[0], xb = xr[1], xc = xr[2], xd = xr[3];
    float  b  = bs[p];

    for (;;) {
        const int curp = p;
        const float4 ca = xa, cb = xb, cc = xc, cd = xd;
        const float  cbv = b;

        // --- prefetch next tile (overlaps the FMA chain below) ---
        const int next = tile + gridDim.x;
        if (next < tiles) {
            p  = next * PROWS + pr;
            const float4* nr = reinterpret_cast<const float4*>(x + p * EMEMB);
            xa = nr[0]; xb = nr[1]; xc = nr[2]; xd = nr[3];
            b  = bs[p];
        }

        // --- m = x_row . W[:, 4g:4g+4]  (64 FMAs, ILP=4) ---
        const float xs[EMEMB] = { ca.x, ca.y, ca.z, ca.w,
                                  cb.x, cb.y, cb.z, cb.w,
                                  cc.x, cc.y, cc.z, cc.w,
                                  cd.x, cd.y, cd.z, cd.w };
        float4 acc = make_float4(0.f, 0.f, 0.f, 0.f);
        #pragma unroll
        for (int k = 0; k < EMEMB; ++k) {
            acc.x = fmaf(xs[k], Wf[k].x, acc.x);
            acc.y = fmaf(xs[k], Wf[k].y, acc.y);
            acc.z = fmaf(xs[k], Wf[k].z, acc.z);
            acc.w = fmaf(xs[k], Wf[k].w, acc.w);
        }

        // out = m + b * m*m  (exactly per reference)
        float4 r;
        r.x = fmaf(cbv * acc.x, acc.x, acc.x);
        r.y = fmaf(cbv * acc.y, acc.y, acc.y);
        r.z = fmaf(cbv * acc.z, acc.z, acc.z);
        r.w = fmaf(cbv * acc.w, acc.w, acc.w);

        *reinterpret_cast<float4*>(out + curp * LBANDS + 4 * g) = r;

        if (next >= tiles) break;
        tile = next;
    }
}

extern "C" void kernel_launch(void* const* d_in, const int* in_sizes, int n_in,
                              void* d_out, int out_size, void* d_ws, size_t ws_size,
                              hipStream_t stream) {
    const float* x  = (const float*)d_in[0];   // [B, 16]
    const float* w  = (const float*)d_in[1];   // [16, 224]
    const float* bs = (const float*)d_in[2];   // [B]
    float* out = (float*)d_out;

    const int B = in_sizes[2];                 // 262144

    // 2048 blocks: 16 tiles each amortize the per-thread W-fragment load;
    // ~2 resident blocks/CU (14 waves) under the 128-VGPR cap.
    const int grid = 2048;
    ppnm_kernel<<<grid, NTHREADS, 0, stream>>>(x, w, bs, out, B);
}